// Round 1
// baseline (440.716 us; speedup 1.0000x reference)
//
#include <hip/hip_runtime.h>
#include <hip/hip_bf16.h>

// Problem constants
#define BB 64
#define TT 1024
#define AA 128
#define FF 1024
#define KW 31
#define DQ 1024
#define DV 512

__device__ __forceinline__ float ftanh(float x) {
    // tanh(x) = 1 - 2/(exp(2x)+1); exact at +-inf, err ~1e-6
    float e = __expf(2.0f * x);
    return 1.0f - 2.0f / (e + 1.0f);
}

// ---------------- K1: q[b,a] = tanh(sum_d query[b,d] * Wq[d,a]) ----------------
__global__ void k_query(const float* __restrict__ query, const float* __restrict__ Wq,
                        float* __restrict__ q_ws) {
    int b = blockIdx.x, a = threadIdx.x;
    const float* qrow = query + b * DQ;
    float a0 = 0.f, a1 = 0.f, a2 = 0.f, a3 = 0.f;
    for (int d = 0; d < DQ; d += 4) {
        float4 qv = *(const float4*)(qrow + d);
        a0 += qv.x * Wq[(d + 0) * AA + a];
        a1 += qv.y * Wq[(d + 1) * AA + a];
        a2 += qv.z * Wq[(d + 2) * AA + a];
        a3 += qv.w * Wq[(d + 3) * AA + a];
    }
    q_ws[b * AA + a] = ftanh(a0 + a1 + a2 + a3);
}

// ---------------- K2: z[b,kc,a] = sum_t x[b, t+k-15, c] * Wloc[t,a] ----------------
// Grid: (16 t-chunks, 4 a-groups, 64 b), 128 threads = 32 a-lanes x 4 k-groups of 8.
// k padded to 32 (k=31 writes to kc 62/63, ignored downstream).
__global__ void k_zconv(const float* __restrict__ xcat, const float* __restrict__ Wloc,
                        float* __restrict__ z_ws) {
    int tcn = blockIdx.x, ag = blockIdx.y, b = blockIdx.z;
    int t0 = tcn * 64;
    int lane = threadIdx.x & 31;
    int kg = threadIdx.x >> 5;  // 0..3
    int a = ag * 32 + lane;
    __shared__ float xs[95 * 2];  // window t0-15 .. t0+79, both channels
    for (int i = threadIdx.x; i < 190; i += 128) {
        int gt = t0 - 15 + (i >> 1);
        int c = i & 1;
        xs[i] = (gt >= 0 && gt < TT) ? xcat[(b * TT + gt) * 2 + c] : 0.f;
    }
    __syncthreads();
    float acc[8][2];
#pragma unroll
    for (int j = 0; j < 8; j++) { acc[j][0] = 0.f; acc[j][1] = 0.f; }
    int kbase = kg * 8;
    for (int tt = 0; tt < 64; tt++) {
        float w = Wloc[(t0 + tt) * AA + a];
#pragma unroll
        for (int j = 0; j < 8; j++) {
            float2 xv = *(const float2*)&xs[(tt + kbase + j) * 2];
            acc[j][0] += xv.x * w;
            acc[j][1] += xv.y * w;
        }
    }
#pragma unroll
    for (int j = 0; j < 8; j++) {
        int k = kbase + j;
        atomicAdd(&z_ws[(b * 64 + 2 * k + 0) * AA + a], acc[j][0]);
        atomicAdd(&z_ws[(b * 64 + 2 * k + 1) * AA + a], acc[j][1]);
    }
}

// ---------------- K3: loc2[b,f,a] = tanh(sum_kc Wconv[kc,f] * z[b,kc,a]) ----------------
// Grid: (16 f-chunks of 64, 64 b), 128 threads (a).
__global__ void k_loc(const float* __restrict__ Wconv, const float* __restrict__ z_ws,
                      float* __restrict__ loc2) {
    int b = blockIdx.y, f0 = blockIdx.x * 64, a = threadIdx.x;
    __shared__ float zs[62 * AA];
    for (int i = threadIdx.x; i < 62 * AA; i += 128) zs[i] = z_ws[b * 64 * AA + i];
    __syncthreads();
    float zr[62];
#pragma unroll
    for (int kc = 0; kc < 62; kc++) zr[kc] = zs[kc * AA + a];
    for (int f = f0; f < f0 + 64; f++) {
        float acc = 0.f;
#pragma unroll
        for (int kc = 0; kc < 62; kc++) acc += Wconv[kc * FF + f] * zr[kc];
        loc2[(size_t)(b * TT + f) * AA + a] = ftanh(acc);
    }
}

// ---------------- K4: v = tanh(value @ Wm); score = sum_a tanh(q+v+loc2)*Wv ----------------
// Grid: 512 blocks (64 b x 8 row-tiles of 128), 256 threads, 8x8 micro-tile.
__global__ __launch_bounds__(256) void k_gemm_score(
    const float* __restrict__ value, const float* __restrict__ Wm,
    const float* __restrict__ q_ws, const float* __restrict__ loc2,
    const float* __restrict__ Wv, float* __restrict__ v_ws, float* __restrict__ score) {
    int b = blockIdx.x >> 3;
    int trow0 = (blockIdx.x & 7) << 7;
    int tid = threadIdx.x;
    int tx = tid & 15, ty = tid >> 4;
    int a0 = tx * 8, r0 = ty * 8;
    __shared__ float vst[32 * 132];  // transposed value tile [dd][t], pad 132
    __shared__ float wmt[32 * 128];  // Wm tile [dd][a]
    float acc[8][8];
#pragma unroll
    for (int i = 0; i < 8; i++)
#pragma unroll
        for (int j = 0; j < 8; j++) acc[i][j] = 0.f;

    for (int d0 = 0; d0 < DV; d0 += 32) {
#pragma unroll
        for (int l = 0; l < 4; l++) {
            int idx = tid + l * 256;           // 0..1023
            int t = idx >> 3, c4 = idx & 7;    // 128 rows x 8 float4
            float4 v4 = *(const float4*)(value + (size_t)(b * TT + trow0 + t) * DV + d0 + c4 * 4);
            vst[(c4 * 4 + 0) * 132 + t] = v4.x;
            vst[(c4 * 4 + 1) * 132 + t] = v4.y;
            vst[(c4 * 4 + 2) * 132 + t] = v4.z;
            vst[(c4 * 4 + 3) * 132 + t] = v4.w;
        }
#pragma unroll
        for (int l = 0; l < 4; l++) {
            int idx = tid + l * 256;
            int r = idx >> 5, c4 = idx & 31;   // 32 rows x 32 float4
            *(float4*)&wmt[r * 128 + c4 * 4] = *(const float4*)(Wm + (d0 + r) * AA + c4 * 4);
        }
        __syncthreads();
#pragma unroll 4
        for (int dd = 0; dd < 32; dd++) {
            float va[8], wa[8];
            *(float4*)&va[0] = *(float4*)&vst[dd * 132 + r0];
            *(float4*)&va[4] = *(float4*)&vst[dd * 132 + r0 + 4];
            *(float4*)&wa[0] = *(float4*)&wmt[dd * 128 + a0];
            *(float4*)&wa[4] = *(float4*)&wmt[dd * 128 + a0 + 4];
#pragma unroll
            for (int i = 0; i < 8; i++)
#pragma unroll
                for (int j = 0; j < 8; j++) acc[i][j] += va[i] * wa[j];
        }
        __syncthreads();
    }

    // Epilogue: tanh -> v_ws; fused score partials + lane reduction over tx.
    float q8[8], wv8[8];
    *(float4*)&q8[0] = *(const float4*)(q_ws + b * AA + a0);
    *(float4*)&q8[4] = *(const float4*)(q_ws + b * AA + a0 + 4);
    *(float4*)&wv8[0] = *(const float4*)(Wv + a0);
    *(float4*)&wv8[4] = *(const float4*)(Wv + a0 + 4);
#pragma unroll
    for (int i = 0; i < 8; i++) {
        int t = trow0 + r0 + i;
        size_t rowoff = (size_t)(b * TT + t) * AA + a0;
        float l2[8];
        *(float4*)&l2[0] = *(const float4*)(loc2 + rowoff);
        *(float4*)&l2[4] = *(const float4*)(loc2 + rowoff + 4);
        float vv[8];
        float s = 0.f;
#pragma unroll
        for (int j = 0; j < 8; j++) {
            vv[j] = ftanh(acc[i][j]);
            s += ftanh(q8[j] + vv[j] + l2[j]) * wv8[j];
        }
        *(float4*)(v_ws + rowoff) = *(float4*)&vv[0];
        *(float4*)(v_ws + rowoff + 4) = *(float4*)&vv[4];
        s += __shfl_xor(s, 1, 64);
        s += __shfl_xor(s, 2, 64);
        s += __shfl_xor(s, 4, 64);
        s += __shfl_xor(s, 8, 64);
        if (tx == 0) score[b * TT + t] = s;
    }
}

// ---------------- K5a: softmax over t ----------------
__global__ void k_softmax(const float* __restrict__ score, float* __restrict__ out_align) {
    int b = blockIdx.x, tid = threadIdx.x;
    __shared__ float red[4];
    float s[4];
#pragma unroll
    for (int i = 0; i < 4; i++) s[i] = score[b * TT + tid + i * 256];
    float m = fmaxf(fmaxf(s[0], s[1]), fmaxf(s[2], s[3]));
    for (int off = 32; off; off >>= 1) m = fmaxf(m, __shfl_xor(m, off, 64));
    int wid = tid >> 6;
    if ((tid & 63) == 0) red[wid] = m;
    __syncthreads();
    float M = fmaxf(fmaxf(red[0], red[1]), fmaxf(red[2], red[3]));
    __syncthreads();
    float e[4];
    float sum = 0.f;
#pragma unroll
    for (int i = 0; i < 4; i++) { e[i] = __expf(s[i] - M); sum += e[i]; }
    for (int off = 32; off; off >>= 1) sum += __shfl_xor(sum, off, 64);
    if ((tid & 63) == 0) red[wid] = sum;
    __syncthreads();
    float inv = 1.0f / (red[0] + red[1] + red[2] + red[3]);
#pragma unroll
    for (int i = 0; i < 4; i++) out_align[b * TT + tid + i * 256] = e[i] * inv;
}

// ---------------- K5b: context[b,a] = sum_t align[b,t] * v[b,t,a] ----------------
__global__ void k_context(const float* __restrict__ align, const float* __restrict__ v_ws,
                          float* __restrict__ out_ctx) {
    int b = blockIdx.y, t0 = blockIdx.x * 128, a = threadIdx.x;
    const float* vb = v_ws + (size_t)(b * TT + t0) * AA + a;
    const float* al = align + b * TT + t0;
    float a0 = 0.f, a1 = 0.f, a2 = 0.f, a3 = 0.f;
    for (int t = 0; t < 128; t += 4) {
        a0 += al[t + 0] * vb[(size_t)(t + 0) * AA];
        a1 += al[t + 1] * vb[(size_t)(t + 1) * AA];
        a2 += al[t + 2] * vb[(size_t)(t + 2) * AA];
        a3 += al[t + 3] * vb[(size_t)(t + 3) * AA];
    }
    atomicAdd(&out_ctx[b * AA + a], a0 + a1 + a2 + a3);
}

extern "C" void kernel_launch(void* const* d_in, const int* in_sizes, int n_in,
                              void* d_out, int out_size, void* d_ws, size_t ws_size,
                              hipStream_t stream) {
    const float* query = (const float*)d_in[0];
    const float* value = (const float*)d_in[1];
    const float* xcat  = (const float*)d_in[2];
    const float* Wq    = (const float*)d_in[3];
    const float* Wm    = (const float*)d_in[4];
    const float* Wv    = (const float*)d_in[5];
    const float* Wconv = (const float*)d_in[6];
    const float* Wloc  = (const float*)d_in[7];
    float* out = (float*)d_out;
    float* ws = (float*)d_ws;

    // ws layout (floats)
    float* q_ws   = ws;                       // 8192
    float* z_ws   = q_ws + 8192;              // 64*64*128 = 524288
    float* sc_ws  = z_ws + 524288;            // 65536
    float* loc2_ws = sc_ws + 65536;           // 64*1024*128 = 8388608
    float* v_ws   = loc2_ws + 8388608;        // 8388608
    // total ~69.5 MB

    hipMemsetAsync(z_ws, 0, (size_t)524288 * 4, stream);
    hipMemsetAsync(out, 0, (size_t)8192 * 4, stream);  // context accumulated via atomics

    k_query<<<BB, 128, 0, stream>>>(query, Wq, q_ws);
    k_zconv<<<dim3(16, 4, BB), 128, 0, stream>>>(xcat, Wloc, z_ws);
    k_loc<<<dim3(16, BB), 128, 0, stream>>>(Wconv, z_ws, loc2_ws);
    k_gemm_score<<<512, 256, 0, stream>>>(value, Wm, q_ws, loc2_ws, Wv, v_ws, sc_ws);
    k_softmax<<<BB, 256, 0, stream>>>(sc_ws, out + 8192);
    k_context<<<dim3(8, BB), 128, 0, stream>>>(out + 8192, v_ws, out);
}

// Round 2
// 392.758 us; speedup vs baseline: 1.1221x; 1.1221x over previous
//
#include <hip/hip_runtime.h>
#include <hip/hip_bf16.h>

#define BB 64
#define TT 1024
#define AA 128
#define FF 1024
#define DQ 1024
#define DV 512

typedef __bf16 bf16x8_t __attribute__((ext_vector_type(8)));
typedef __bf16 bf16x4_t __attribute__((ext_vector_type(4)));
typedef float f32x4_t __attribute__((ext_vector_type(4)));

__device__ __forceinline__ float ftanh(float x) {
    float e = __expf(2.0f * x);
    return 1.0f - 2.0f / (e + 1.0f);
}

// ---------------- K0: transpose Wm -> bf16 hi/lo [a][d]; Wconv -> wct [f][64] ----------------
__global__ void k_prep(const float* __restrict__ Wm, const float* __restrict__ Wconv,
                       __bf16* __restrict__ wmhi, __bf16* __restrict__ wmlo,
                       __bf16* __restrict__ wcthi, __bf16* __restrict__ wctlo) {
    int idx = blockIdx.x * 256 + threadIdx.x;
    if (idx < DV * AA) {
        int d = idx >> 7, a = idx & 127;
        float x = Wm[idx];
        __bf16 h = (__bf16)x;
        wmhi[a * DV + d] = h;
        wmlo[a * DV + d] = (__bf16)(x - (float)h);
    } else {
        int j = idx - DV * AA;  // f*64 + kc
        int f = j >> 6, kc = j & 63;
        float x = (kc < 62) ? Wconv[kc * FF + f] : 0.f;
        __bf16 h = (__bf16)x;
        wcthi[j] = h;
        wctlo[j] = (__bf16)(x - (float)h);
    }
}

// ---------------- K1: q[b,a] = tanh(sum_d query[b,d] * Wq[d,a]) ----------------
__global__ void k_query(const float* __restrict__ query, const float* __restrict__ Wq,
                        float* __restrict__ q_ws) {
    int b = blockIdx.x;
    int a = threadIdx.x & 127, half = threadIdx.x >> 7;
    const float* qrow = query + b * DQ + half * 512;
    float a0 = 0.f, a1 = 0.f, a2 = 0.f, a3 = 0.f;
    for (int d = 0; d < 512; d += 4) {
        float4 qv = *(const float4*)(qrow + d);
        int dg = (half * 512 + d) * AA + a;
        a0 += qv.x * Wq[dg];
        a1 += qv.y * Wq[dg + AA];
        a2 += qv.z * Wq[dg + 2 * AA];
        a3 += qv.w * Wq[dg + 3 * AA];
    }
    __shared__ float part[256];
    part[threadIdx.x] = a0 + a1 + a2 + a3;
    __syncthreads();
    if (half == 0) q_ws[b * AA + a] = ftanh(part[a] + part[a + 128]);
}

// ---------------- K2: z[b,kc,a] -> transposed bf16 hi/lo [b][a][64], no atomics ----------------
// Grid: (4 a-groups, 64 b), 256 threads = 32 a-lanes x 8 k-groups of 4.
__global__ void k_zconv(const float* __restrict__ xcat, const float* __restrict__ Wloc,
                        __bf16* __restrict__ zthi, __bf16* __restrict__ ztlo) {
    int ag = blockIdx.x, b = blockIdx.y;
    int lane = threadIdx.x & 31;
    int kg = threadIdx.x >> 5;  // 0..7
    int a = ag * 32 + lane;
    __shared__ float xs[190];
    float acc[4][2];
#pragma unroll
    for (int j = 0; j < 4; j++) { acc[j][0] = 0.f; acc[j][1] = 0.f; }
    for (int tc = 0; tc < 16; tc++) {
        int t0 = tc * 64;
        __syncthreads();
        if (threadIdx.x < 190) {
            int i = threadIdx.x;
            int gt = t0 - 15 + (i >> 1);
            int c = i & 1;
            xs[i] = (gt >= 0 && gt < TT) ? xcat[(b * TT + gt) * 2 + c] : 0.f;
        }
        __syncthreads();
        for (int tt = 0; tt < 64; tt++) {
            float w = Wloc[(t0 + tt) * AA + a];
#pragma unroll
            for (int j = 0; j < 4; j++) {
                int k = kg * 4 + j;
                float2 xv = *(const float2*)&xs[(tt + k) * 2];
                acc[j][0] += xv.x * w;
                acc[j][1] += xv.y * w;
            }
        }
    }
#pragma unroll
    for (int j = 0; j < 4; j++) {
#pragma unroll
        for (int c = 0; c < 2; c++) {
            int kc = 2 * (kg * 4 + j) + c;
            float z = acc[j][c];
            __bf16 h = (__bf16)z;
            zthi[(b * AA + a) * 64 + kc] = h;
            ztlo[(b * AA + a) * 64 + kc] = (__bf16)(z - (float)h);
        }
    }
}

// ---------------- K3: MFMA: v = tanh(value@Wm), loc = tanh(wct@z), fused score ----------------
// Block: 128 t-rows x 128 a. 4 waves (2x2), each 64x64 via 16 mfma_16x16x32 tiles.
__global__ __launch_bounds__(256, 2) void k_gemm_mfma(
    const float* __restrict__ value,
    const __bf16* __restrict__ wmhi, const __bf16* __restrict__ wmlo,
    const __bf16* __restrict__ wcthi, const __bf16* __restrict__ wctlo,
    const __bf16* __restrict__ zthi, const __bf16* __restrict__ ztlo,
    const float* __restrict__ q_ws, const float* __restrict__ Wv,
    float* __restrict__ v_ws, float* __restrict__ score) {
    int b = blockIdx.x >> 3;
    int trow0 = (blockIdx.x & 7) << 7;
    int tid = threadIdx.x;
    int lane = tid & 63, wid = tid >> 6;
    int wm = wid >> 1, wn = wid & 1;
    int l15 = lane & 15, lq = lane >> 4;

    __shared__ __bf16 as_hi[128 * 40];
    __shared__ __bf16 as_lo[128 * 40];
    __shared__ float sc_red[256];

    f32x4_t acc[4][4];
#pragma unroll
    for (int mi = 0; mi < 4; mi++)
#pragma unroll
        for (int ni = 0; ni < 4; ni++) acc[mi][ni] = (f32x4_t){0.f, 0.f, 0.f, 0.f};

    // ---- main K loop: v_pre = value @ Wm (3-term bf16 split) ----
    const float* vbase = value + (size_t)(b * TT + trow0) * DV;
    for (int d0 = 0; d0 < DV; d0 += 32) {
#pragma unroll
        for (int l = 0; l < 4; l++) {
            int idx = tid + l * 256;
            int t = idx >> 3, c4 = idx & 7;
            float4 v4 = *(const float4*)(vbase + (size_t)t * DV + d0 + c4 * 4);
            __bf16 h0 = (__bf16)v4.x, h1 = (__bf16)v4.y, h2 = (__bf16)v4.z, h3 = (__bf16)v4.w;
            bf16x4_t hv = {h0, h1, h2, h3};
            bf16x4_t lv = {(__bf16)(v4.x - (float)h0), (__bf16)(v4.y - (float)h1),
                           (__bf16)(v4.z - (float)h2), (__bf16)(v4.w - (float)h3)};
            *(bf16x4_t*)(as_hi + t * 40 + c4 * 4) = hv;
            *(bf16x4_t*)(as_lo + t * 40 + c4 * 4) = lv;
        }
        __syncthreads();
        bf16x8_t ah[4], al[4], bh[4], bl[4];
#pragma unroll
        for (int ni = 0; ni < 4; ni++) {
            int a = wn * 64 + ni * 16 + l15;
            size_t off = (size_t)a * DV + d0 + lq * 8;
            bh[ni] = *(const bf16x8_t*)(wmhi + off);
            bl[ni] = *(const bf16x8_t*)(wmlo + off);
        }
#pragma unroll
        for (int mi = 0; mi < 4; mi++) {
            int off2 = (wm * 64 + mi * 16 + l15) * 40 + lq * 8;
            ah[mi] = *(const bf16x8_t*)(as_hi + off2);
            al[mi] = *(const bf16x8_t*)(as_lo + off2);
        }
#pragma unroll
        for (int mi = 0; mi < 4; mi++)
#pragma unroll
            for (int ni = 0; ni < 4; ni++) {
                acc[mi][ni] = __builtin_amdgcn_mfma_f32_16x16x32_bf16(ah[mi], bh[ni], acc[mi][ni], 0, 0, 0);
                acc[mi][ni] = __builtin_amdgcn_mfma_f32_16x16x32_bf16(al[mi], bh[ni], acc[mi][ni], 0, 0, 0);
                acc[mi][ni] = __builtin_amdgcn_mfma_f32_16x16x32_bf16(ah[mi], bl[ni], acc[mi][ni], 0, 0, 0);
            }
        __syncthreads();
    }

    // ---- loc gemm: loc_pre = wct[t][kc] @ z[kc][a], K = 64 (kc 62/63 zero-padded) ----
    f32x4_t lacc[4][4];
#pragma unroll
    for (int mi = 0; mi < 4; mi++)
#pragma unroll
        for (int ni = 0; ni < 4; ni++) lacc[mi][ni] = (f32x4_t){0.f, 0.f, 0.f, 0.f};
#pragma unroll
    for (int kc0 = 0; kc0 < 64; kc0 += 32) {
        bf16x8_t a2h[4], a2l[4], b2h[4], b2l[4];
#pragma unroll
        for (int mi = 0; mi < 4; mi++) {
            int f = trow0 + wm * 64 + mi * 16 + l15;
            a2h[mi] = *(const bf16x8_t*)(wcthi + f * 64 + kc0 + lq * 8);
            a2l[mi] = *(const bf16x8_t*)(wctlo + f * 64 + kc0 + lq * 8);
        }
#pragma unroll
        for (int ni = 0; ni < 4; ni++) {
            int a = wn * 64 + ni * 16 + l15;
            b2h[ni] = *(const bf16x8_t*)(zthi + (b * AA + a) * 64 + kc0 + lq * 8);
            b2l[ni] = *(const bf16x8_t*)(ztlo + (b * AA + a) * 64 + kc0 + lq * 8);
        }
#pragma unroll
        for (int mi = 0; mi < 4; mi++)
#pragma unroll
            for (int ni = 0; ni < 4; ni++) {
                lacc[mi][ni] = __builtin_amdgcn_mfma_f32_16x16x32_bf16(a2h[mi], b2h[ni], lacc[mi][ni], 0, 0, 0);
                lacc[mi][ni] = __builtin_amdgcn_mfma_f32_16x16x32_bf16(a2l[mi], b2h[ni], lacc[mi][ni], 0, 0, 0);
                lacc[mi][ni] = __builtin_amdgcn_mfma_f32_16x16x32_bf16(a2h[mi], b2l[ni], lacc[mi][ni], 0, 0, 0);
            }
    }

    // ---- epilogue: v = tanh(acc) -> v_ws; score = sum_a tanh(q + v + tanh(lacc)) * Wv ----
    float qv[4], wv[4];
#pragma unroll
    for (int ni = 0; ni < 4; ni++) {
        int a = wn * 64 + ni * 16 + l15;
        qv[ni] = q_ws[b * AA + a];
        wv[ni] = Wv[a];
    }
#pragma unroll
    for (int mi = 0; mi < 4; mi++) {
#pragma unroll
        for (int r = 0; r < 4; r++) {
            int tl = wm * 64 + mi * 16 + lq * 4 + r;
            int t = trow0 + tl;
            float s = 0.f;
#pragma unroll
            for (int ni = 0; ni < 4; ni++) {
                float v = ftanh(acc[mi][ni][r]);
                float loc = ftanh(lacc[mi][ni][r]);
                int a = wn * 64 + ni * 16 + l15;
                v_ws[(size_t)(b * TT + t) * AA + a] = v;
                s += ftanh(qv[ni] + v + loc) * wv[ni];
            }
            s += __shfl_xor(s, 1, 64);
            s += __shfl_xor(s, 2, 64);
            s += __shfl_xor(s, 4, 64);
            s += __shfl_xor(s, 8, 64);
            if (l15 == 0) sc_red[wn * 128 + tl] = s;
        }
    }
    __syncthreads();
    if (tid < 128) score[b * TT + trow0 + tid] = sc_red[tid] + sc_red[128 + tid];
}

// ---------------- K4: softmax over t ----------------
__global__ void k_softmax(const float* __restrict__ score, float* __restrict__ out_align) {
    int b = blockIdx.x, tid = threadIdx.x;
    __shared__ float red[4];
    float s[4];
#pragma unroll
    for (int i = 0; i < 4; i++) s[i] = score[b * TT + tid + i * 256];
    float m = fmaxf(fmaxf(s[0], s[1]), fmaxf(s[2], s[3]));
    for (int off = 32; off; off >>= 1) m = fmaxf(m, __shfl_xor(m, off, 64));
    int wid = tid >> 6;
    if ((tid & 63) == 0) red[wid] = m;
    __syncthreads();
    float M = fmaxf(fmaxf(red[0], red[1]), fmaxf(red[2], red[3]));
    __syncthreads();
    float e[4];
    float sum = 0.f;
#pragma unroll
    for (int i = 0; i < 4; i++) { e[i] = __expf(s[i] - M); sum += e[i]; }
    for (int off = 32; off; off >>= 1) sum += __shfl_xor(sum, off, 64);
    if ((tid & 63) == 0) red[wid] = sum;
    __syncthreads();
    float inv = 1.0f / (red[0] + red[1] + red[2] + red[3]);
#pragma unroll
    for (int i = 0; i < 4; i++) out_align[b * TT + tid + i * 256] = e[i] * inv;
}

// ---------------- K5: context[b,a] = sum_t align[b,t] * v[b,t,a] ----------------
__global__ void k_context(const float* __restrict__ align, const float* __restrict__ v_ws,
                          float* __restrict__ out_ctx) {
    int b = blockIdx.y, t0 = blockIdx.x * 128, a = threadIdx.x;
    const float* vb = v_ws + (size_t)(b * TT + t0) * AA + a;
    const float* al = align + b * TT + t0;
    float a0 = 0.f, a1 = 0.f, a2 = 0.f, a3 = 0.f;
    for (int t = 0; t < 128; t += 4) {
        a0 += al[t + 0] * vb[(size_t)(t + 0) * AA];
        a1 += al[t + 1] * vb[(size_t)(t + 1) * AA];
        a2 += al[t + 2] * vb[(size_t)(t + 2) * AA];
        a3 += al[t + 3] * vb[(size_t)(t + 3) * AA];
    }
    atomicAdd(&out_ctx[b * AA + a], a0 + a1 + a2 + a3);
}

extern "C" void kernel_launch(void* const* d_in, const int* in_sizes, int n_in,
                              void* d_out, int out_size, void* d_ws, size_t ws_size,
                              hipStream_t stream) {
    const float* query = (const float*)d_in[0];
    const float* value = (const float*)d_in[1];
    const float* xcat  = (const float*)d_in[2];
    const float* Wq    = (const float*)d_in[3];
    const float* Wm    = (const float*)d_in[4];
    const float* Wv    = (const float*)d_in[5];
    const float* Wconv = (const float*)d_in[6];
    const float* Wloc  = (const float*)d_in[7];
    float* out = (float*)d_out;

    float* ws = (float*)d_ws;
    float* q_ws  = ws;                   // 8192
    float* sc_ws = q_ws + 8192;          // 65536
    float* v_ws  = sc_ws + 65536;        // 8388608
    __bf16* wmhi  = (__bf16*)(v_ws + 8388608);
    __bf16* wmlo  = wmhi + 65536;
    __bf16* wcthi = wmlo + 65536;
    __bf16* wctlo = wcthi + 65536;
    __bf16* zthi  = wctlo + 65536;       // 524288
    __bf16* ztlo  = zthi + 524288;

    hipMemsetAsync(out, 0, (size_t)8192 * 4, stream);  // context accumulated via atomics

    k_prep<<<512, 256, 0, stream>>>(Wm, Wconv, wmhi, wmlo, wcthi, wctlo);
    k_query<<<BB, 256, 0, stream>>>(query, Wq, q_ws);
    k_zconv<<<dim3(4, BB), 256, 0, stream>>>(xcat, Wloc, zthi, ztlo);
    k_gemm_mfma<<<512, 256, 0, stream>>>(value, wmhi, wmlo, wcthi, wctlo, zthi, ztlo,
                                         q_ws, Wv, v_ws, sc_ws);
    k_softmax<<<BB, 256, 0, stream>>>(sc_ws, out + 8192);
    k_context<<<dim3(8, BB), 128, 0, stream>>>(out + 8192, v_ws, out);
}

// Round 3
// 299.481 us; speedup vs baseline: 1.4716x; 1.3115x over previous
//
#include <hip/hip_runtime.h>
#include <hip/hip_bf16.h>

#define BB 64
#define TT 1024
#define AA 128
#define FF 1024
#define DQ 1024
#define DV 512

typedef __bf16 bf16x8_t __attribute__((ext_vector_type(8)));
typedef __bf16 bf16x4_t __attribute__((ext_vector_type(4)));
typedef float f32x4_t __attribute__((ext_vector_type(4)));

__device__ __forceinline__ float ftanh(float x) {
    float e = __expf(2.0f * x);
    return 1.0f - 2.0f / (e + 1.0f);
}

// ---------------- K_pre: fused zconv-pass1 (blocks 0..4095), prep (4096..4607), query (4608..4671) ----------------
// zconv pass1: zpart[tc][b][kc][a] = sum over 64 t of x[b,t+k-15,c]*Wloc[t,a]
__global__ __launch_bounds__(256) void k_pre(
    const float* __restrict__ xcat, const float* __restrict__ Wloc,
    const float* __restrict__ Wm, const float* __restrict__ Wconv,
    const float* __restrict__ query, const float* __restrict__ Wq,
    float* __restrict__ zpart,
    __bf16* __restrict__ wmhi, __bf16* __restrict__ wmlo,
    __bf16* __restrict__ wcthi, __bf16* __restrict__ wctlo,
    float* __restrict__ q_ws) {
    __shared__ float sh[256];
    int bx = blockIdx.x;
    int tid = threadIdx.x;
    if (bx < 4096) {
        // ---- zconv pass 1: (tc, ag, b) ----
        int b = bx & 63, ag = (bx >> 6) & 3, tc = bx >> 8;
        int t0 = tc * 64;
        int lane = tid & 31, kg = tid >> 5;  // 32 a-lanes x 8 k-groups
        int a = ag * 32 + lane;
        if (tid < 190) {
            int gt = t0 - 15 + (tid >> 1);
            int c = tid & 1;
            sh[tid] = (gt >= 0 && gt < TT) ? xcat[(b * TT + gt) * 2 + c] : 0.f;
        }
        __syncthreads();
        float acc[4][2];
#pragma unroll
        for (int j = 0; j < 4; j++) { acc[j][0] = 0.f; acc[j][1] = 0.f; }
        for (int tt = 0; tt < 64; tt++) {
            float w = Wloc[(t0 + tt) * AA + a];
#pragma unroll
            for (int j = 0; j < 4; j++) {
                int k = kg * 4 + j;
                float2 xv = *(const float2*)&sh[(tt + k) * 2];
                acc[j][0] += xv.x * w;
                acc[j][1] += xv.y * w;
            }
        }
#pragma unroll
        for (int j = 0; j < 4; j++)
#pragma unroll
            for (int c = 0; c < 2; c++) {
                int kc = 2 * (kg * 4 + j) + c;
                zpart[(((size_t)tc * 64 + b) * 64 + kc) * 128 + a] = acc[j][c];
            }
    } else if (bx < 4608) {
        // ---- prep: transpose Wm -> [a][d] hi/lo; Wconv -> wct[f][64] hi/lo ----
        int idx = (bx - 4096) * 256 + tid;
        if (idx < DV * AA) {
            int d = idx >> 7, a = idx & 127;
            float x = Wm[idx];
            __bf16 h = (__bf16)x;
            wmhi[a * DV + d] = h;
            wmlo[a * DV + d] = (__bf16)(x - (float)h);
        } else {
            int j = idx - DV * AA;  // f*64 + kc
            int f = j >> 6, kc = j & 63;
            float x = (kc < 62) ? Wconv[kc * FF + f] : 0.f;
            __bf16 h = (__bf16)x;
            wcthi[j] = h;
            wctlo[j] = (__bf16)(x - (float)h);
        }
    } else {
        // ---- query: q[b,a] = tanh(sum_d query[b,d]*Wq[d,a]) ----
        int b = bx - 4608;
        int a = tid & 127, half = tid >> 7;
        const float* qrow = query + b * DQ + half * 512;
        float a0 = 0.f, a1 = 0.f, a2 = 0.f, a3 = 0.f;
        for (int d = 0; d < 512; d += 4) {
            float4 qv = *(const float4*)(qrow + d);
            int dg = (half * 512 + d) * AA + a;
            a0 += qv.x * Wq[dg];
            a1 += qv.y * Wq[dg + AA];
            a2 += qv.z * Wq[dg + 2 * AA];
            a3 += qv.w * Wq[dg + 3 * AA];
        }
        sh[tid] = a0 + a1 + a2 + a3;
        __syncthreads();
        if (half == 0) q_ws[b * AA + a] = ftanh(sh[a] + sh[a + 128]);
    }
}

// ---------------- K_zfin: reduce zpart over tc, transpose -> bf16 hi/lo [b][a][64] ----------------
// Grid (4 kc-quarters, 64 b), 256 threads.
__global__ void k_zfin(const float* __restrict__ zpart,
                       __bf16* __restrict__ zthi, __bf16* __restrict__ ztlo) {
    int q = blockIdx.x, b = blockIdx.y;
    int tid = threadIdx.x;
    __shared__ float zs[16 * 129];
    int slot0 = tid * 8;
    int kc_l = slot0 >> 7;    // 0..15
    int a0 = slot0 & 127;
    float s[8];
#pragma unroll
    for (int i = 0; i < 8; i++) s[i] = 0.f;
    for (int tc = 0; tc < 16; tc++) {
        const float* p = zpart + (((size_t)tc * 64 + b) * 64 + q * 16 + kc_l) * 128 + a0;
        float4 u0 = *(const float4*)p;
        float4 u1 = *(const float4*)(p + 4);
        s[0] += u0.x; s[1] += u0.y; s[2] += u0.z; s[3] += u0.w;
        s[4] += u1.x; s[5] += u1.y; s[6] += u1.z; s[7] += u1.w;
    }
#pragma unroll
    for (int i = 0; i < 8; i++) zs[kc_l * 129 + a0 + i] = s[i];
    __syncthreads();
    int a = tid >> 1, half = tid & 1;
    bf16x8_t h8, l8;
#pragma unroll
    for (int j = 0; j < 8; j++) {
        float x = zs[(half * 8 + j) * 129 + a];
        __bf16 h = (__bf16)x;
        h8[j] = h;
        l8[j] = (__bf16)(x - (float)h);
    }
    size_t off = ((size_t)b * 128 + a) * 64 + q * 16 + half * 8;
    *(bf16x8_t*)(zthi + off) = h8;
    *(bf16x8_t*)(ztlo + off) = l8;
}

// ---------------- K3: MFMA: v = tanh(value@Wm), loc = tanh(wct@z), fused score ----------------
__global__ __launch_bounds__(256, 2) void k_gemm_mfma(
    const float* __restrict__ value,
    const __bf16* __restrict__ wmhi, const __bf16* __restrict__ wmlo,
    const __bf16* __restrict__ wcthi, const __bf16* __restrict__ wctlo,
    const __bf16* __restrict__ zthi, const __bf16* __restrict__ ztlo,
    const float* __restrict__ q_ws, const float* __restrict__ Wv,
    float* __restrict__ v_ws, float* __restrict__ score) {
    int b = blockIdx.x >> 3;
    int trow0 = (blockIdx.x & 7) << 7;
    int tid = threadIdx.x;
    int lane = tid & 63, wid = tid >> 6;
    int wm = wid >> 1, wn = wid & 1;
    int l15 = lane & 15, lq = lane >> 4;

    __shared__ __bf16 as_hi[128 * 40];
    __shared__ __bf16 as_lo[128 * 40];
    __shared__ float sc_red[256];

    f32x4_t acc[4][4];
#pragma unroll
    for (int mi = 0; mi < 4; mi++)
#pragma unroll
        for (int ni = 0; ni < 4; ni++) acc[mi][ni] = (f32x4_t){0.f, 0.f, 0.f, 0.f};

    const float* vbase = value + (size_t)(b * TT + trow0) * DV;
    int t0r = tid >> 3, c4 = tid & 7;

    // prologue: prefetch first value tile into registers
    float4 cur[4];
#pragma unroll
    for (int l = 0; l < 4; l++)
        cur[l] = *(const float4*)(vbase + (size_t)(t0r + 32 * l) * DV + c4 * 4);

    for (int it = 0; it < 16; ++it) {
        int d0 = it * 32;
        __syncthreads();  // prev iter's LDS reads complete before overwrite
#pragma unroll
        for (int l = 0; l < 4; l++) {
            int t = t0r + 32 * l;
            float4 v4 = cur[l];
            __bf16 h0 = (__bf16)v4.x, h1 = (__bf16)v4.y, h2 = (__bf16)v4.z, h3 = (__bf16)v4.w;
            *(bf16x4_t*)(as_hi + t * 40 + c4 * 4) = (bf16x4_t){h0, h1, h2, h3};
            *(bf16x4_t*)(as_lo + t * 40 + c4 * 4) =
                (bf16x4_t){(__bf16)(v4.x - (float)h0), (__bf16)(v4.y - (float)h1),
                           (__bf16)(v4.z - (float)h2), (__bf16)(v4.w - (float)h3)};
        }
        __syncthreads();
        // prefetch next tile (overlaps with MFMA below)
        if (it < 15) {
#pragma unroll
            for (int l = 0; l < 4; l++)
                cur[l] = *(const float4*)(vbase + (size_t)(t0r + 32 * l) * DV + d0 + 32 + c4 * 4);
        }
        bf16x8_t ah[4], al[4], bh[4], bl[4];
#pragma unroll
        for (int ni = 0; ni < 4; ni++) {
            int a = wn * 64 + ni * 16 + l15;
            size_t off = (size_t)a * DV + d0 + lq * 8;
            bh[ni] = *(const bf16x8_t*)(wmhi + off);
            bl[ni] = *(const bf16x8_t*)(wmlo + off);
        }
#pragma unroll
        for (int mi = 0; mi < 4; mi++) {
            int off2 = (wm * 64 + mi * 16 + l15) * 40 + lq * 8;
            ah[mi] = *(const bf16x8_t*)(as_hi + off2);
            al[mi] = *(const bf16x8_t*)(as_lo + off2);
        }
#pragma unroll
        for (int mi = 0; mi < 4; mi++)
#pragma unroll
            for (int ni = 0; ni < 4; ni++) {
                acc[mi][ni] = __builtin_amdgcn_mfma_f32_16x16x32_bf16(ah[mi], bh[ni], acc[mi][ni], 0, 0, 0);
                acc[mi][ni] = __builtin_amdgcn_mfma_f32_16x16x32_bf16(al[mi], bh[ni], acc[mi][ni], 0, 0, 0);
                acc[mi][ni] = __builtin_amdgcn_mfma_f32_16x16x32_bf16(ah[mi], bl[ni], acc[mi][ni], 0, 0, 0);
            }
    }

    // ---- loc gemm: loc_pre = wct[t][kc] @ z[kc][a], K=64 (kc 62/63 zero in wct) ----
    f32x4_t lacc[4][4];
#pragma unroll
    for (int mi = 0; mi < 4; mi++)
#pragma unroll
        for (int ni = 0; ni < 4; ni++) lacc[mi][ni] = (f32x4_t){0.f, 0.f, 0.f, 0.f};
#pragma unroll
    for (int kc0 = 0; kc0 < 64; kc0 += 32) {
        bf16x8_t a2h[4], a2l[4], b2h[4], b2l[4];
#pragma unroll
        for (int mi = 0; mi < 4; mi++) {
            int f = trow0 + wm * 64 + mi * 16 + l15;
            a2h[mi] = *(const bf16x8_t*)(wcthi + f * 64 + kc0 + lq * 8);
            a2l[mi] = *(const bf16x8_t*)(wctlo + f * 64 + kc0 + lq * 8);
        }
#pragma unroll
        for (int ni = 0; ni < 4; ni++) {
            int a = wn * 64 + ni * 16 + l15;
            b2h[ni] = *(const bf16x8_t*)(zthi + (b * AA + a) * 64 + kc0 + lq * 8);
            b2l[ni] = *(const bf16x8_t*)(ztlo + (b * AA + a) * 64 + kc0 + lq * 8);
        }
#pragma unroll
        for (int mi = 0; mi < 4; mi++)
#pragma unroll
            for (int ni = 0; ni < 4; ni++) {
                lacc[mi][ni] = __builtin_amdgcn_mfma_f32_16x16x32_bf16(a2h[mi], b2h[ni], lacc[mi][ni], 0, 0, 0);
                lacc[mi][ni] = __builtin_amdgcn_mfma_f32_16x16x32_bf16(a2l[mi], b2h[ni], lacc[mi][ni], 0, 0, 0);
                lacc[mi][ni] = __builtin_amdgcn_mfma_f32_16x16x32_bf16(a2h[mi], b2l[ni], lacc[mi][ni], 0, 0, 0);
            }
    }

    // ---- epilogue ----
    float qv[4], wv[4];
#pragma unroll
    for (int ni = 0; ni < 4; ni++) {
        int a = wn * 64 + ni * 16 + l15;
        qv[ni] = q_ws[b * AA + a];
        wv[ni] = Wv[a];
    }
#pragma unroll
    for (int mi = 0; mi < 4; mi++) {
#pragma unroll
        for (int r = 0; r < 4; r++) {
            int tl = wm * 64 + mi * 16 + lq * 4 + r;
            int t = trow0 + tl;
            float s = 0.f;
#pragma unroll
            for (int ni = 0; ni < 4; ni++) {
                float v = ftanh(acc[mi][ni][r]);
                float loc = ftanh(lacc[mi][ni][r]);
                int a = wn * 64 + ni * 16 + l15;
                v_ws[(size_t)(b * TT + t) * AA + a] = v;
                s += ftanh(qv[ni] + v + loc) * wv[ni];
            }
            s += __shfl_xor(s, 1, 64);
            s += __shfl_xor(s, 2, 64);
            s += __shfl_xor(s, 4, 64);
            s += __shfl_xor(s, 8, 64);
            if (l15 == 0) sc_red[wn * 128 + tl] = s;
        }
    }
    __syncthreads();
    if (tid < 128) score[b * TT + trow0 + tid] = sc_red[tid] + sc_red[128 + tid];
}

// ---------------- K4: softmax over t ----------------
__global__ void k_softmax(const float* __restrict__ score, float* __restrict__ out_align) {
    int b = blockIdx.x, tid = threadIdx.x;
    __shared__ float red[4];
    float s[4];
#pragma unroll
    for (int i = 0; i < 4; i++) s[i] = score[b * TT + tid + i * 256];
    float m = fmaxf(fmaxf(s[0], s[1]), fmaxf(s[2], s[3]));
    for (int off = 32; off; off >>= 1) m = fmaxf(m, __shfl_xor(m, off, 64));
    int wid = tid >> 6;
    if ((tid & 63) == 0) red[wid] = m;
    __syncthreads();
    float M = fmaxf(fmaxf(red[0], red[1]), fmaxf(red[2], red[3]));
    __syncthreads();
    float e[4];
    float sum = 0.f;
#pragma unroll
    for (int i = 0; i < 4; i++) { e[i] = __expf(s[i] - M); sum += e[i]; }
    for (int off = 32; off; off >>= 1) sum += __shfl_xor(sum, off, 64);
    if ((tid & 63) == 0) red[wid] = sum;
    __syncthreads();
    float inv = 1.0f / (red[0] + red[1] + red[2] + red[3]);
#pragma unroll
    for (int i = 0; i < 4; i++) out_align[b * TT + tid + i * 256] = e[i] * inv;
}

// ---------------- K5: context[b,a] = sum_t align[b,t] * v[b,t,a] ----------------
__global__ void k_context(const float* __restrict__ align, const float* __restrict__ v_ws,
                          float* __restrict__ out_ctx) {
    int b = blockIdx.y, t0 = blockIdx.x * 64, a = threadIdx.x;
    const float* vb = v_ws + (size_t)(b * TT + t0) * AA + a;
    const float* al = align + b * TT + t0;
    float a0 = 0.f, a1 = 0.f, a2 = 0.f, a3 = 0.f;
    for (int t = 0; t < 64; t += 4) {
        a0 += al[t + 0] * vb[(size_t)(t + 0) * AA];
        a1 += al[t + 1] * vb[(size_t)(t + 1) * AA];
        a2 += al[t + 2] * vb[(size_t)(t + 2) * AA];
        a3 += al[t + 3] * vb[(size_t)(t + 3) * AA];
    }
    atomicAdd(&out_ctx[b * AA + a], a0 + a1 + a2 + a3);
}

extern "C" void kernel_launch(void* const* d_in, const int* in_sizes, int n_in,
                              void* d_out, int out_size, void* d_ws, size_t ws_size,
                              hipStream_t stream) {
    const float* query = (const float*)d_in[0];
    const float* value = (const float*)d_in[1];
    const float* xcat  = (const float*)d_in[2];
    const float* Wq    = (const float*)d_in[3];
    const float* Wm    = (const float*)d_in[4];
    const float* Wv    = (const float*)d_in[5];
    const float* Wconv = (const float*)d_in[6];
    const float* Wloc  = (const float*)d_in[7];
    float* out = (float*)d_out;

    float* ws = (float*)d_ws;
    float* q_ws  = ws;                   // 8192
    float* sc_ws = q_ws + 8192;          // 65536
    float* v_ws  = sc_ws + 65536;        // 8388608 floats; ALSO aliased as zpart
    float* zpart = v_ws;                 // lifetime: k_pre -> k_zfin (before gemm writes v_ws)
    __bf16* wmhi  = (__bf16*)(v_ws + 8388608);
    __bf16* wmlo  = wmhi + 65536;
    __bf16* wcthi = wmlo + 65536;
    __bf16* wctlo = wcthi + 65536;
    __bf16* zthi  = wctlo + 65536;       // 524288
    __bf16* ztlo  = zthi + 524288;

    hipMemsetAsync(out, 0, (size_t)8192 * 4, stream);  // context accumulated via atomics

    k_pre<<<4672, 256, 0, stream>>>(xcat, Wloc, Wm, Wconv, query, Wq,
                                    zpart, wmhi, wmlo, wcthi, wctlo, q_ws);
    k_zfin<<<dim3(4, BB), 256, 0, stream>>>(zpart, zthi, ztlo);
    k_gemm_mfma<<<512, 256, 0, stream>>>(value, wmhi, wmlo, wcthi, wctlo, zthi, ztlo,
                                         q_ws, Wv, v_ws, sc_ws);
    k_softmax<<<BB, 256, 0, stream>>>(sc_ws, out + 8192);
    k_context<<<dim3(16, BB), 128, 0, stream>>>(out + 8192, v_ws, out);
}